// Round 2
// baseline (213.254 us; speedup 1.0000x reference)
//
#include <hip/hip_runtime.h>
#include <math.h>

#define Bz 32
#define Sz 4096
#define Hz 32
#define Gz 2
#define Dz 128
#define HIDz 4096
#define QKVz 4608
#define NU 32   // flash units per (b,g): 128 rows each

static __device__ __forceinline__ void fma4(float4& a, float s, const float4& v) {
  a.x = fmaf(s, v.x, a.x);
  a.y = fmaf(s, v.y, a.y);
  a.z = fmaf(s, v.z, a.z);
  a.w = fmaf(s, v.w, a.w);
}

// ---------------- split-K GEMM partial: part[kt][b][j] = sum_{k in chunk} X[b][k]*W[k][j]
__global__ __launch_bounds__(256) void gemm_partial(
    const float* __restrict__ X, const float* __restrict__ W,
    float* __restrict__ part, int K, int N, int KH) {
  extern __shared__ float hl[];  // [32][KH+4]
  const int stride = KH + 4;
  const int t = threadIdx.x;
  const int k0 = blockIdx.y * KH;
  const int cols4 = KH >> 2;
  const int total4 = Bz * cols4;
  for (int fi = t; fi < total4; fi += 256) {
    const int row = fi / cols4;
    const int c4 = fi - row * cols4;
    const float4 v = *(const float4*)&X[(size_t)row * K + k0 + c4 * 4];
    *(float4*)&hl[row * stride + c4 * 4] = v;
  }
  __syncthreads();
  const int jl = t & 63;
  const int b0 = (t >> 6) * 8;
  const int j = blockIdx.x * 256 + jl * 4;
  float4 acc[8];
  #pragma unroll
  for (int i = 0; i < 8; i++) acc[i] = make_float4(0.f, 0.f, 0.f, 0.f);
  for (int kk = 0; kk < KH; kk += 4) {
    const float4 w0 = *(const float4*)&W[(size_t)(k0 + kk + 0) * N + j];
    const float4 w1 = *(const float4*)&W[(size_t)(k0 + kk + 1) * N + j];
    const float4 w2 = *(const float4*)&W[(size_t)(k0 + kk + 2) * N + j];
    const float4 w3 = *(const float4*)&W[(size_t)(k0 + kk + 3) * N + j];
    #pragma unroll
    for (int bi = 0; bi < 8; bi++) {
      const float4 hb = *(const float4*)&hl[(b0 + bi) * stride + kk];
      fma4(acc[bi], hb.x, w0);
      fma4(acc[bi], hb.y, w1);
      fma4(acc[bi], hb.z, w2);
      fma4(acc[bi], hb.w, w3);
    }
  }
  #pragma unroll
  for (int bi = 0; bi < 8; bi++) {
    *(float4*)&part[((size_t)blockIdx.y * Bz + b0 + bi) * N + j] = acc[bi];
  }
}

// ---------------- reduce QKV partials + bias, RoPE, emit qrot (pre-scaled), krot, vnew
__global__ __launch_bounds__(256) void qkv_finish(
    const float* __restrict__ part, const float* __restrict__ bias,
    const int* __restrict__ positions, int KT,
    float* __restrict__ qrot, float* __restrict__ krot, float* __restrict__ vnew) {
  const int t = threadIdx.x;
  const int b = blockIdx.x;
  const int head = blockIdx.y * 4 + (t >> 6);
  const int tp = t & 63;
  const int j0 = head * Dz + tp * 2;
  float s0 = bias[j0];
  float s1 = bias[j0 + 1];
  for (int kt = 0; kt < KT; kt++) {
    const float2 p = *(const float2*)&part[((size_t)kt * Bz + b) * QKVz + j0];
    s0 += p.x;
    s1 += p.y;
  }
  float o0 = s0, o1 = s1;
  if (head < Hz + Gz && tp < 32) {
    const float invf = exp2f(-(float)tp * (13.287712379549449f / 32.0f));
    const float a = (float)positions[b] * invf;
    float sn, cs;
    sincosf(a, &sn, &cs);
    o0 = s0 * cs - s1 * sn;
    o1 = s1 * cs + s0 * sn;
  }
  if (head < Hz) {
    const float sc = 0.08838834764831845f;
    float2 o = make_float2(o0 * sc, o1 * sc);
    *(float2*)&qrot[((size_t)b * Hz + head) * Dz + tp * 2] = o;
  } else if (head < Hz + Gz) {
    float2 o = make_float2(o0, o1);
    *(float2*)&krot[((size_t)b * Gz + (head - Hz)) * Dz + tp * 2] = o;
  } else {
    float2 o = make_float2(s0, s1);
    *(float2*)&vnew[((size_t)b * Gz + (head - Hz - Gz)) * Dz + tp * 2] = o;
  }
}

// ---------------- wave-autonomous flash unit: each wave handles 128 KV rows for 16 heads.
// Lane tile QK: 4 heads (hq) x 4 rows (sq). Lane tile PV: 4 heads x 8 d (df==sq bits).
// K/V stream global->registers; Q broadcast from LDS; P handoff via wave-private LDS.
// grid (8, G, B), block 256 = 4 waves = units u = bx*4 + w.
__global__ __launch_bounds__(256) void attn_unit(
    const float* __restrict__ qrot, const float* __restrict__ kcache,
    const float* __restrict__ vcache, const float* __restrict__ krot,
    const float* __restrict__ vnew, const int* __restrict__ positions,
    float* __restrict__ mbuf, float* __restrict__ lbuf, float* __restrict__ pacc) {
  __shared__ float ql[16 * 132];   // padded stride 132
  __shared__ float pl[4][16 * 68]; // per-wave P buffer, stride 68
  const int g = blockIdx.y, b = blockIdx.z;
  const int pos = positions[b];
  if ((int)blockIdx.x * 512 > pos) return;  // whole block beyond valid range
  const int t = threadIdx.x;
  for (int i = t; i < 16 * 32; i += 256) {
    const int row = i >> 5, c4 = i & 31;
    *(float4*)&ql[row * 132 + c4 * 4] =
        *(const float4*)&qrot[((size_t)b * Hz + g * 16 + row) * Dz + c4 * 4];
  }
  __syncthreads();  // only barrier in this kernel

  const int w = t >> 6;
  const int u = blockIdx.x * 4 + w;
  const int srow0 = u * 128;
  if (srow0 > pos) return;  // wave-uniform exit, no barriers follow
  const int lane = t & 63;
  const int hq = lane >> 4;
  const int sq = lane & 15;
  float* plw = pl[w];
  const float* krow_new = &krot[((size_t)b * Gz + g) * Dz];
  const float* vrow_new = &vnew[((size_t)b * Gz + g) * Dz];
  const size_t kvb = ((size_t)b * Sz) * (Gz * Dz) + (size_t)g * Dz;  // + s*(Gz*Dz)

  float m_run[4], l_run[4];
  float4 A[4][2];
  #pragma unroll
  for (int i = 0; i < 4; i++) {
    m_run[i] = -1e30f;
    l_run[i] = 0.f;
    A[i][0] = make_float4(0.f, 0.f, 0.f, 0.f);
    A[i][1] = make_float4(0.f, 0.f, 0.f, 0.f);
  }

  for (int t2 = 0; t2 < 2; ++t2) {
    const int sb = srow0 + t2 * 64;
    if (sb > pos) break;
    const int nv = pos + 1 - sb;  // >=1; rows >= nv are masked
    // ---- QK^T: lane computes 4 heads x 4 rows over full d
    const float* kp[4];
    #pragma unroll
    for (int r = 0; r < 4; ++r) {
      const int sg = sb + sq * 4 + r;
      kp[r] = (sg == pos) ? krow_new : &kcache[kvb + (size_t)sg * (Gz * Dz)];
    }
    float acc[4][4];
    #pragma unroll
    for (int i = 0; i < 4; i++)
      #pragma unroll
      for (int r = 0; r < 4; r++) acc[i][r] = 0.f;
    #pragma unroll 2
    for (int d4 = 0; d4 < 32; ++d4) {
      const float4 k0 = *(const float4*)&kp[0][d4 * 4];
      const float4 k1 = *(const float4*)&kp[1][d4 * 4];
      const float4 k2 = *(const float4*)&kp[2][d4 * 4];
      const float4 k3 = *(const float4*)&kp[3][d4 * 4];
      #pragma unroll
      for (int i = 0; i < 4; ++i) {
        const float4 q = *(const float4*)&ql[(hq * 4 + i) * 132 + d4 * 4];
        acc[i][0] = fmaf(q.x, k0.x, fmaf(q.y, k0.y, fmaf(q.z, k0.z, fmaf(q.w, k0.w, acc[i][0]))));
        acc[i][1] = fmaf(q.x, k1.x, fmaf(q.y, k1.y, fmaf(q.z, k1.z, fmaf(q.w, k1.w, acc[i][1]))));
        acc[i][2] = fmaf(q.x, k2.x, fmaf(q.y, k2.y, fmaf(q.z, k2.z, fmaf(q.w, k2.w, acc[i][2]))));
        acc[i][3] = fmaf(q.x, k3.x, fmaf(q.y, k3.y, fmaf(q.z, k3.z, fmaf(q.w, k3.w, acc[i][3]))));
      }
    }
    // mask invalid rows
    #pragma unroll
    for (int r = 0; r < 4; ++r) {
      if (sq * 4 + r >= nv) {
        #pragma unroll
        for (int i = 0; i < 4; ++i) acc[i][r] = -1e30f;
      }
    }
    // ---- online softmax per head (within 16-lane segment)
    #pragma unroll
    for (int i = 0; i < 4; ++i) {
      float tm = fmaxf(fmaxf(acc[i][0], acc[i][1]), fmaxf(acc[i][2], acc[i][3]));
      tm = fmaxf(tm, __shfl_xor(tm, 1, 16));
      tm = fmaxf(tm, __shfl_xor(tm, 2, 16));
      tm = fmaxf(tm, __shfl_xor(tm, 4, 16));
      tm = fmaxf(tm, __shfl_xor(tm, 8, 16));
      const float mn = fmaxf(m_run[i], tm);
      const float sc = __expf(m_run[i] - mn);
      m_run[i] = mn;
      const float p0 = __expf(acc[i][0] - mn);
      const float p1 = __expf(acc[i][1] - mn);
      const float p2 = __expf(acc[i][2] - mn);
      const float p3 = __expf(acc[i][3] - mn);
      float ts = (p0 + p1) + (p2 + p3);
      ts += __shfl_xor(ts, 1, 16);
      ts += __shfl_xor(ts, 2, 16);
      ts += __shfl_xor(ts, 4, 16);
      ts += __shfl_xor(ts, 8, 16);
      l_run[i] = l_run[i] * sc + ts;
      A[i][0].x *= sc; A[i][0].y *= sc; A[i][0].z *= sc; A[i][0].w *= sc;
      A[i][1].x *= sc; A[i][1].y *= sc; A[i][1].z *= sc; A[i][1].w *= sc;
      float4 pv = make_float4(p0, p1, p2, p3);
      *(float4*)&plw[(hq * 4 + i) * 68 + sq * 4] = pv;
    }
    // ---- PV: lane = 4 heads (hq) x 8 d (df = sq)
    for (int s4 = 0; s4 < 16; ++s4) {
      float P[4][4];
      #pragma unroll
      for (int i = 0; i < 4; ++i) {
        const float4 f = *(const float4*)&plw[(hq * 4 + i) * 68 + s4 * 4];
        P[i][0] = f.x; P[i][1] = f.y; P[i][2] = f.z; P[i][3] = f.w;
      }
      #pragma unroll
      for (int r = 0; r < 4; ++r) {
        const int sg = sb + s4 * 4 + r;
        const float* vp = (sg == pos) ? vrow_new : &vcache[kvb + (size_t)sg * (Gz * Dz)];
        const float4 va = *(const float4*)&vp[sq * 8];
        const float4 vb = *(const float4*)&vp[sq * 8 + 4];
        #pragma unroll
        for (int i = 0; i < 4; ++i) {
          fma4(A[i][0], P[i][r], va);
          fma4(A[i][1], P[i][r], vb);
        }
      }
    }
  }
  // ---- write unit partials
  const size_t ub = (size_t)(b * Gz + g) * NU + u;
  #pragma unroll
  for (int i = 0; i < 4; ++i) {
    *(float4*)&pacc[ub * 2048 + (size_t)(hq * 4 + i) * 128 + sq * 8] = A[i][0];
    *(float4*)&pacc[ub * 2048 + (size_t)(hq * 4 + i) * 128 + sq * 8 + 4] = A[i][1];
  }
  if (sq == 0) {
    #pragma unroll
    for (int i = 0; i < 4; ++i) {
      mbuf[ub * 16 + hq * 4 + i] = m_run[i];
      lbuf[ub * 16 + hq * 4 + i] = l_run[i];
    }
  }
}

// ---------------- combine unit partials -> ctx (B, H*D)
__global__ __launch_bounds__(512) void attn_combine(
    const float* __restrict__ mbuf, const float* __restrict__ lbuf,
    const float* __restrict__ pacc, const int* __restrict__ positions,
    float* __restrict__ ctx) {
  const int bg = blockIdx.x;
  const int b = bg >> 1, g = bg & 1;
  const int t = threadIdx.x;
  const int h = t >> 5, dg = t & 31;
  const int nc = positions[b] / 128 + 1;
  const size_t mlb = (size_t)bg * NU * 16 + h;
  float mstar = -1e30f;
  for (int c = 0; c < nc; c++) mstar = fmaxf(mstar, mbuf[mlb + c * 16]);
  float lsum = 0.f;
  float4 A = make_float4(0.f, 0.f, 0.f, 0.f);
  for (int c = 0; c < nc; c++) {
    const float w = __expf(mbuf[mlb + c * 16] - mstar);
    lsum += w * lbuf[mlb + c * 16];
    const float4 p = *(const float4*)&pacc[((size_t)bg * NU + c) * 2048 + (size_t)h * Dz + dg * 4];
    fma4(A, w, p);
  }
  const float inv = 1.0f / lsum;
  float4 o = make_float4(A.x * inv, A.y * inv, A.z * inv, A.w * inv);
  *(float4*)&ctx[(size_t)b * (Hz * Dz) + (g * 16 + h) * Dz + dg * 4] = o;
}

// ---------------- reduce dense partials -> out
__global__ __launch_bounds__(256) void reduce_out(
    const float* __restrict__ part, float* __restrict__ out, int KT) {
  const int idx = blockIdx.x * 256 + threadIdx.x;
  const int b = idx >> 12;
  const int j = idx & 4095;
  float s = 0.f;
  for (int kt = 0; kt < KT; kt++) s += part[((size_t)kt * Bz + b) * HIDz + j];
  out[idx] = s;
}

extern "C" void kernel_launch(void* const* d_in, const int* in_sizes, int n_in,
                              void* d_out, int out_size, void* d_ws, size_t ws_size,
                              hipStream_t stream) {
  const float* hidden = (const float*)d_in[0];
  const int* positions = (const int*)d_in[1];
  const float* kcache = (const float*)d_in[2];
  const float* vcache = (const float*)d_in[3];
  const float* Wqkv = (const float*)d_in[4];
  const float* bqkv = (const float*)d_in[5];
  const float* Wd = (const float*)d_in[6];
  float* out = (float*)d_out;

  auto need = [](int KT) -> size_t {
    return (size_t)KT * Bz * QKVz
         + (size_t)Bz * Hz * Dz
         + (size_t)Bz * Gz * Dz * 2
         + (size_t)Bz * Gz * NU * 16 * 2
         + (size_t)Bz * Gz * NU * 2048
         + (size_t)Bz * HIDz;
  };
  int KT = 32;
  if (need(32) * sizeof(float) > ws_size) KT = 16;
  const int KH = HIDz / KT;

  float* w = (float*)d_ws;
  float* p1 = w;    w += (size_t)KT * Bz * QKVz;
  float* qrot = w;  w += (size_t)Bz * Hz * Dz;
  float* krot = w;  w += (size_t)Bz * Gz * Dz;
  float* vnew = w;  w += (size_t)Bz * Gz * Dz;
  float* mbuf = w;  w += (size_t)Bz * Gz * NU * 16;
  float* lbuf = w;  w += (size_t)Bz * Gz * NU * 16;
  float* pacc = w;  w += (size_t)Bz * Gz * NU * 2048;
  float* ctx = w;

  const size_t smem = (size_t)Bz * (KH + 4) * sizeof(float);

  gemm_partial<<<dim3(QKVz / 256, KT), 256, smem, stream>>>(hidden, Wqkv, p1, HIDz, QKVz, KH);
  qkv_finish<<<dim3(Bz, 9), 256, 0, stream>>>(p1, bqkv, positions, KT, qrot, krot, vnew);
  attn_unit<<<dim3(8, Gz, Bz), 256, 0, stream>>>(qrot, kcache, vcache, krot, vnew, positions,
                                                 mbuf, lbuf, pacc);
  attn_combine<<<dim3(Bz * Gz), 512, 0, stream>>>(mbuf, lbuf, pacc, positions, ctx);
  gemm_partial<<<dim3(HIDz / 256, KT), 256, smem, stream>>>(ctx, Wd, p1, Hz * Dz, HIDz, KH);
  reduce_out<<<dim3(Bz * HIDz / 256), 256, 0, stream>>>(p1, out, KT);
}

// Round 3
// 176.326 us; speedup vs baseline: 1.2094x; 1.2094x over previous
//
#include <hip/hip_runtime.h>
#include <math.h>

#define Bz 32
#define Sz 4096
#define Hz 32
#define Gz 2
#define Dz 128
#define HIDz 4096
#define QKVz 4608
#define NCHc 16   // combine chunks per (b,g): blocks of 256 rows

static __device__ __forceinline__ void fma4(float4& a, float s, const float4& v) {
  a.x = fmaf(s, v.x, a.x);
  a.y = fmaf(s, v.y, a.y);
  a.z = fmaf(s, v.z, a.z);
  a.w = fmaf(s, v.w, a.w);
}

// ---------------- split-K GEMM partial: part[kt][b][j] = sum_{k in chunk} X[b][k]*W[k][j]
// grid (N/128, KT), block 256. Thread: 4 j-cols x 4 b-rows.
__global__ __launch_bounds__(256) void gemm_partial(
    const float* __restrict__ X, const float* __restrict__ W,
    float* __restrict__ part, int K, int N, int KH) {
  extern __shared__ float hl[];  // [32][KH+4]
  const int stride = KH + 4;
  const int t = threadIdx.x;
  const int k0 = blockIdx.y * KH;
  const int cols4 = KH >> 2;
  const int total4 = Bz * cols4;
  for (int fi = t; fi < total4; fi += 256) {
    const int row = fi / cols4;
    const int c4 = fi - row * cols4;
    const float4 v = *(const float4*)&X[(size_t)row * K + k0 + c4 * 4];
    *(float4*)&hl[row * stride + c4 * 4] = v;
  }
  __syncthreads();
  const int jl = t & 31;
  const int b0 = (t >> 5) * 4;
  const int j = blockIdx.x * 128 + jl * 4;
  float4 acc[4];
  #pragma unroll
  for (int i = 0; i < 4; i++) acc[i] = make_float4(0.f, 0.f, 0.f, 0.f);
  #pragma unroll 4
  for (int kk = 0; kk < KH; kk += 4) {
    const float4 w0 = *(const float4*)&W[(size_t)(k0 + kk + 0) * N + j];
    const float4 w1 = *(const float4*)&W[(size_t)(k0 + kk + 1) * N + j];
    const float4 w2 = *(const float4*)&W[(size_t)(k0 + kk + 2) * N + j];
    const float4 w3 = *(const float4*)&W[(size_t)(k0 + kk + 3) * N + j];
    #pragma unroll
    for (int bi = 0; bi < 4; bi++) {
      const float4 hb = *(const float4*)&hl[(b0 + bi) * stride + kk];
      fma4(acc[bi], hb.x, w0);
      fma4(acc[bi], hb.y, w1);
      fma4(acc[bi], hb.z, w2);
      fma4(acc[bi], hb.w, w3);
    }
  }
  #pragma unroll
  for (int bi = 0; bi < 4; bi++) {
    *(float4*)&part[((size_t)blockIdx.y * Bz + b0 + bi) * N + j] = acc[bi];
  }
}

// ---------------- reduce QKV partials + bias, RoPE, emit qrot (pre-scaled), krot, vnew
__global__ __launch_bounds__(256) void qkv_finish(
    const float* __restrict__ part, const float* __restrict__ bias,
    const int* __restrict__ positions, int KT,
    float* __restrict__ qrot, float* __restrict__ krot, float* __restrict__ vnew) {
  const int t = threadIdx.x;
  const int b = blockIdx.x;
  const int head = blockIdx.y * 4 + (t >> 6);
  const int tp = t & 63;
  const int j0 = head * Dz + tp * 2;
  float s0 = bias[j0];
  float s1 = bias[j0 + 1];
  for (int kt = 0; kt < KT; kt++) {
    const float2 p = *(const float2*)&part[((size_t)kt * Bz + b) * QKVz + j0];
    s0 += p.x;
    s1 += p.y;
  }
  float o0 = s0, o1 = s1;
  if (head < Hz + Gz && tp < 32) {
    const float invf = exp2f(-(float)tp * (13.287712379549449f / 32.0f));
    const float a = (float)positions[b] * invf;
    float sn, cs;
    sincosf(a, &sn, &cs);
    o0 = s0 * cs - s1 * sn;
    o1 = s1 * cs + s0 * sn;
  }
  if (head < Hz) {
    const float sc = 0.08838834764831845f;
    float2 o = make_float2(o0 * sc, o1 * sc);
    *(float2*)&qrot[((size_t)b * Hz + head) * Dz + tp * 2] = o;
  } else if (head < Hz + Gz) {
    float2 o = make_float2(o0, o1);
    *(float2*)&krot[((size_t)b * Gz + (head - Hz)) * Dz + tp * 2] = o;
  } else {
    float2 o = make_float2(s0, s1);
    *(float2*)&vnew[((size_t)b * Gz + (head - Hz - Gz)) * Dz + tp * 2] = o;
  }
}

// ---------------- flash unit: wave = 64 KV rows x 16 heads; 4 waves/block combine in LDS.
// grid (16, G, B), block 256. Lane tile QK: 4 heads x 4 rows. PV: 4 heads x 8 d.
__global__ __launch_bounds__(256) void attn_unit(
    const float* __restrict__ qrot, const float* __restrict__ kcache,
    const float* __restrict__ vcache, const float* __restrict__ krot,
    const float* __restrict__ vnew, const int* __restrict__ positions,
    float* __restrict__ mbuf, float* __restrict__ lbuf, float* __restrict__ pacc) {
  __shared__ float smem[8448];
  // phase A: ql = smem[0..2112), pl[w] = smem[2112 + w*1088 ..)
  // phase B (after barrier, aliased): Aw[w] = smem[w*2064..), ml = smem[8256..8384)
  float* ql = smem;
  const int g = blockIdx.y, b = blockIdx.z;
  const int pos = positions[b];
  if ((int)blockIdx.x * 256 > pos) return;  // uniform: whole block out of range
  const int t = threadIdx.x;
  for (int i = t; i < 16 * 32; i += 256) {
    const int row = i >> 5, c4 = i & 31;
    *(float4*)&ql[row * 132 + c4 * 4] =
        *(const float4*)&qrot[((size_t)b * Hz + g * 16 + row) * Dz + c4 * 4];
  }
  __syncthreads();

  const int w = t >> 6;
  const int lane = t & 63;
  const int hq = lane >> 4;
  const int sq = lane & 15;
  float* plw = smem + 2112 + w * 1088;  // [16][68] wave-private
  const int srow0 = (blockIdx.x * 4 + w) * 64;

  float m_run[4], l_run[4];
  float4 A[4][2];
  #pragma unroll
  for (int i = 0; i < 4; i++) {
    m_run[i] = -1e30f;
    l_run[i] = 0.f;
    A[i][0] = make_float4(0.f, 0.f, 0.f, 0.f);
    A[i][1] = make_float4(0.f, 0.f, 0.f, 0.f);
  }

  if (srow0 <= pos) {
    const int nv = min(64, pos + 1 - srow0);
    const float* krow_new = &krot[((size_t)b * Gz + g) * Dz];
    const float* vrow_new = &vnew[((size_t)b * Gz + g) * Dz];
    const size_t kvb = ((size_t)b * Sz) * (Gz * Dz) + (size_t)g * Dz;

    const float* kp[4];
    #pragma unroll
    for (int r = 0; r < 4; ++r) {
      const int sg = srow0 + sq * 4 + r;
      kp[r] = (sg == pos) ? krow_new : &kcache[kvb + (size_t)sg * (Gz * Dz)];
    }
    float acc[4][4];
    #pragma unroll
    for (int i = 0; i < 4; i++)
      #pragma unroll
      for (int r = 0; r < 4; r++) acc[i][r] = 0.f;

    // ---- QK^T with 2-deep K prefetch pipeline
    float4 ka[4], kb[4];
#define LOADK(buf, d4)                                   \
    {                                                    \
      buf[0] = *(const float4*)&kp[0][(d4) * 4];         \
      buf[1] = *(const float4*)&kp[1][(d4) * 4];         \
      buf[2] = *(const float4*)&kp[2][(d4) * 4];         \
      buf[3] = *(const float4*)&kp[3][(d4) * 4];         \
    }
#define QKSTEP(buf, d4)                                                                        \
    {                                                                                          \
      _Pragma("unroll")                                                                        \
      for (int i = 0; i < 4; ++i) {                                                            \
        const float4 q = *(const float4*)&ql[(hq * 4 + i) * 132 + (d4) * 4];                   \
        acc[i][0] = fmaf(q.x, buf[0].x, fmaf(q.y, buf[0].y, fmaf(q.z, buf[0].z, fmaf(q.w, buf[0].w, acc[i][0])))); \
        acc[i][1] = fmaf(q.x, buf[1].x, fmaf(q.y, buf[1].y, fmaf(q.z, buf[1].z, fmaf(q.w, buf[1].w, acc[i][1])))); \
        acc[i][2] = fmaf(q.x, buf[2].x, fmaf(q.y, buf[2].y, fmaf(q.z, buf[2].z, fmaf(q.w, buf[2].w, acc[i][2])))); \
        acc[i][3] = fmaf(q.x, buf[3].x, fmaf(q.y, buf[3].y, fmaf(q.z, buf[3].z, fmaf(q.w, buf[3].w, acc[i][3])))); \
      }                                                                                        \
    }
    LOADK(ka, 0);
    #pragma unroll
    for (int d4 = 0; d4 < 32; d4 += 2) {
      LOADK(kb, d4 + 1);
      QKSTEP(ka, d4);
      if (d4 + 2 < 32) LOADK(ka, d4 + 2);
      QKSTEP(kb, d4 + 1);
    }
#undef LOADK
#undef QKSTEP
    // mask invalid rows
    #pragma unroll
    for (int r = 0; r < 4; ++r) {
      if (sq * 4 + r >= nv) {
        #pragma unroll
        for (int i = 0; i < 4; ++i) acc[i][r] = -1e30f;
      }
    }
    // ---- softmax (single tile, within 16-lane segment)
    #pragma unroll
    for (int i = 0; i < 4; ++i) {
      float tm = fmaxf(fmaxf(acc[i][0], acc[i][1]), fmaxf(acc[i][2], acc[i][3]));
      tm = fmaxf(tm, __shfl_xor(tm, 1, 16));
      tm = fmaxf(tm, __shfl_xor(tm, 2, 16));
      tm = fmaxf(tm, __shfl_xor(tm, 4, 16));
      tm = fmaxf(tm, __shfl_xor(tm, 8, 16));
      m_run[i] = tm;
      const float p0 = __expf(acc[i][0] - tm);
      const float p1 = __expf(acc[i][1] - tm);
      const float p2 = __expf(acc[i][2] - tm);
      const float p3 = __expf(acc[i][3] - tm);
      float ts = (p0 + p1) + (p2 + p3);
      ts += __shfl_xor(ts, 1, 16);
      ts += __shfl_xor(ts, 2, 16);
      ts += __shfl_xor(ts, 4, 16);
      ts += __shfl_xor(ts, 8, 16);
      l_run[i] = ts;
      *(float4*)&plw[(hq * 4 + i) * 68 + sq * 4] = make_float4(p0, p1, p2, p3);
    }
    // ---- PV
    #pragma unroll 2
    for (int s4 = 0; s4 < 16; ++s4) {
      float4 P[4];
      #pragma unroll
      for (int i = 0; i < 4; ++i) P[i] = *(const float4*)&plw[(hq * 4 + i) * 68 + s4 * 4];
      #pragma unroll
      for (int r = 0; r < 4; ++r) {
        const int sg = srow0 + s4 * 4 + r;
        const float* vp = (sg == pos) ? vrow_new : &vcache[kvb + (size_t)sg * (Gz * Dz)];
        const float4 va = *(const float4*)&vp[sq * 8];
        const float4 vb = *(const float4*)&vp[sq * 8 + 4];
        #pragma unroll
        for (int i = 0; i < 4; ++i) {
          const float pr = ((const float*)&P[i])[r];
          fma4(A[i][0], pr, va);
          fma4(A[i][1], pr, vb);
        }
      }
    }
  }

  // ---- in-block combine of 4 wave partials
  __syncthreads();  // all reads of ql/pl done
  float* Aw = smem;            // [4][2064]
  float* ml = smem + 8256;     // [4][32]: m at [h], l at [16+h]
  #pragma unroll
  for (int i = 0; i < 4; ++i) {
    *(float4*)&Aw[w * 2064 + (hq * 4 + i) * 128 + sq * 8] = A[i][0];
    *(float4*)&Aw[w * 2064 + (hq * 4 + i) * 128 + sq * 8 + 4] = A[i][1];
  }
  if (sq == 0) {
    #pragma unroll
    for (int i = 0; i < 4; ++i) {
      ml[w * 32 + hq * 4 + i] = m_run[i];
      ml[w * 32 + 16 + hq * 4 + i] = l_run[i];
    }
  }
  __syncthreads();
  const size_t cb = (size_t)(b * Gz + g) * NCHc + blockIdx.x;
  for (int o = t; o < 512; o += 256) {
    const int h = o >> 5, d4c = o & 31;
    const float m0 = ml[0 * 32 + h], m1 = ml[1 * 32 + h];
    const float m2 = ml[2 * 32 + h], m3 = ml[3 * 32 + h];
    const float ms = fmaxf(fmaxf(m0, m1), fmaxf(m2, m3));
    const float e0 = __expf(m0 - ms), e1 = __expf(m1 - ms);
    const float e2 = __expf(m2 - ms), e3 = __expf(m3 - ms);
    float4 a = make_float4(0.f, 0.f, 0.f, 0.f);
    fma4(a, e0, *(const float4*)&Aw[0 * 2064 + h * 128 + d4c * 4]);
    fma4(a, e1, *(const float4*)&Aw[1 * 2064 + h * 128 + d4c * 4]);
    fma4(a, e2, *(const float4*)&Aw[2 * 2064 + h * 128 + d4c * 4]);
    fma4(a, e3, *(const float4*)&Aw[3 * 2064 + h * 128 + d4c * 4]);
    *(float4*)&pacc[cb * 2048 + (size_t)h * Dz + d4c * 4] = a;
    if (d4c == 0) {
      const float l = e0 * ml[0 * 32 + 16 + h] + e1 * ml[1 * 32 + 16 + h] +
                      e2 * ml[2 * 32 + 16 + h] + e3 * ml[3 * 32 + 16 + h];
      mbuf[cb * 16 + h] = ms;
      lbuf[cb * 16 + h] = l;
    }
  }
}

// ---------------- combine chunk partials -> ctx (B, H*D)
__global__ __launch_bounds__(512) void attn_combine(
    const float* __restrict__ mbuf, const float* __restrict__ lbuf,
    const float* __restrict__ pacc, const int* __restrict__ positions,
    float* __restrict__ ctx) {
  const int bg = blockIdx.x;
  const int b = bg >> 1, g = bg & 1;
  const int t = threadIdx.x;
  const int h = t >> 5, dg = t & 31;
  const int nc = positions[b] / 256 + 1;
  const size_t mlb = (size_t)bg * NCHc * 16 + h;
  float mstar = -1e30f;
  for (int c = 0; c < nc; c++) mstar = fmaxf(mstar, mbuf[mlb + c * 16]);
  float lsum = 0.f;
  float4 A = make_float4(0.f, 0.f, 0.f, 0.f);
  for (int c = 0; c < nc; c++) {
    const float wv = __expf(mbuf[mlb + c * 16] - mstar);
    lsum += wv * lbuf[mlb + c * 16];
    const float4 p = *(const float4*)&pacc[((size_t)bg * NCHc + c) * 2048 + (size_t)h * Dz + dg * 4];
    fma4(A, wv, p);
  }
  const float inv = 1.0f / lsum;
  float4 o = make_float4(A.x * inv, A.y * inv, A.z * inv, A.w * inv);
  *(float4*)&ctx[(size_t)b * (Hz * Dz) + (g * 16 + h) * Dz + dg * 4] = o;
}

// ---------------- reduce dense partials -> out
__global__ __launch_bounds__(256) void reduce_out(
    const float* __restrict__ part, float* __restrict__ out, int KT) {
  const int idx = blockIdx.x * 256 + threadIdx.x;
  const int b = idx >> 12;
  const int j = idx & 4095;
  float s = 0.f;
  for (int kt = 0; kt < KT; kt++) s += part[((size_t)kt * Bz + b) * HIDz + j];
  out[idx] = s;
}

extern "C" void kernel_launch(void* const* d_in, const int* in_sizes, int n_in,
                              void* d_out, int out_size, void* d_ws, size_t ws_size,
                              hipStream_t stream) {
  const float* hidden = (const float*)d_in[0];
  const int* positions = (const int*)d_in[1];
  const float* kcache = (const float*)d_in[2];
  const float* vcache = (const float*)d_in[3];
  const float* Wqkv = (const float*)d_in[4];
  const float* bqkv = (const float*)d_in[5];
  const float* Wd = (const float*)d_in[6];
  float* out = (float*)d_out;

  auto need = [](int KT) -> size_t {
    return (size_t)KT * Bz * QKVz
         + (size_t)Bz * Hz * Dz
         + (size_t)Bz * Gz * Dz * 2
         + (size_t)Bz * Gz * NCHc * 16 * 2
         + (size_t)Bz * Gz * NCHc * 2048
         + (size_t)Bz * HIDz;
  };
  int KT = 32;
  if (need(32) * sizeof(float) > ws_size) KT = 16;
  const int KH = HIDz / KT;

  float* w = (float*)d_ws;
  float* p1 = w;    w += (size_t)KT * Bz * QKVz;
  float* qrot = w;  w += (size_t)Bz * Hz * Dz;
  float* krot = w;  w += (size_t)Bz * Gz * Dz;
  float* vnew = w;  w += (size_t)Bz * Gz * Dz;
  float* mbuf = w;  w += (size_t)Bz * Gz * NCHc * 16;
  float* lbuf = w;  w += (size_t)Bz * Gz * NCHc * 16;
  float* pacc = w;  w += (size_t)Bz * Gz * NCHc * 2048;
  float* ctx = w;

  const size_t smem = (size_t)Bz * (KH + 4) * sizeof(float);

  gemm_partial<<<dim3(QKVz / 128, KT), 256, smem, stream>>>(hidden, Wqkv, p1, HIDz, QKVz, KH);
  qkv_finish<<<dim3(Bz, 9), 256, 0, stream>>>(p1, bqkv, positions, KT, qrot, krot, vnew);
  attn_unit<<<dim3(16, Gz, Bz), 256, 0, stream>>>(qrot, kcache, vcache, krot, vnew, positions,
                                                  mbuf, lbuf, pacc);
  attn_combine<<<dim3(Bz * Gz), 512, 0, stream>>>(mbuf, lbuf, pacc, positions, ctx);
  gemm_partial<<<dim3(HIDz / 128, KT), 256, smem, stream>>>(ctx, Wd, p1, Hz * Dz, HIDz, KH);
  reduce_out<<<dim3(Bz * HIDz / 256), 256, 0, stream>>>(p1, out, KT);
}